// Round 7
// baseline (234.770 us; speedup 1.0000x reference)
//
#include <hip/hip_runtime.h>

typedef _Float16 half_t;
typedef half_t f16x8 __attribute__((ext_vector_type(8)));
typedef float f32x4 __attribute__((ext_vector_type(4)));

#define LOG2E 1.44269504088896340736f

// Problem dims (fixed)
#define NROWS 65536
#define DIN   64
#define NCTRS 1024
#define DOUT  256

// Workspace layout (bytes). ONE FRAGMENT = 64 lanes x 16 B = 1024 B.
#define CSWZ_OFF 0
#define CSWZ_BYTES (128 * 1024)
#define VSWZ_OFF (CSWZ_OFF + CSWZ_BYTES)            // 131072
#define VSWZ_BYTES (512 * 1024)
#define CSQ_OFF  (VSWZ_OFF + VSWZ_BYTES)            // 655360; end 659456

#define CT_STRIDE 68

// ---------------------------------------------------------------------------
// Precompute, 256 blocks: c = bid & 31, part = bid >> 5.
// Each block converts a 32x32 slice of V for chunk c (douts part*32..+31) into
// 2 Vswz frags. part==0 blocks additionally do Cswz + csq for chunk c.
// Fragment layout (A/B symmetric): lane holds [idx=lane&15][k=8*(lane>>4)+j].
// ---------------------------------------------------------------------------
__global__ __launch_bounds__(256) void precompute_kernel(
    const float* __restrict__ ctrs, const float* __restrict__ values,
    const float* __restrict__ s, char* __restrict__ ws) {
  half_t* Cswz = (half_t*)(ws + CSWZ_OFF);
  half_t* Vswz = (half_t*)(ws + VSWZ_OFF);
  float* csq2 = (float*)(ws + CSQ_OFF);

  __shared__ half_t Vt[32 * 36];         // 32 x 32 (+4 pad)
  __shared__ half_t Ct[32 * CT_STRIDE];  // 32 x 64 (padded)

  const int bid = blockIdx.x, tid = threadIdx.x;
  const int c = bid & 31, part = bid >> 5;
  const int w = tid >> 6, l = tid & 63, l4 = l >> 4, lm = l & 15;

  {  // V subtile: rows c*32..+31, douts part*32..+31 -> 256 float4 (1/thread)
    int r = tid >> 3, f4 = tid & 7;
    float4 v = ((const float4*)values)[(size_t)(c * 32 + r) * 64 + part * 8 + f4];
    half_t* d = Vt + r * 36 + f4 * 4;
    d[0] = (half_t)v.x; d[1] = (half_t)v.y;
    d[2] = (half_t)v.z; d[3] = (half_t)v.w;
  }
  if (part == 0) {
    // C tile: 32x64 floats = 512 float4, 2 per thread
#pragma unroll
    for (int i = 0; i < 2; ++i) {
      int idx = i * 256 + tid;
      int r = idx >> 4, c4 = (idx & 15) * 4;
      float4 v = ((const float4*)ctrs)[(size_t)(c * 32 + r) * 16 + (idx & 15)];
      Ct[r * CT_STRIDE + c4 + 0] = (half_t)v.x;
      Ct[r * CT_STRIDE + c4 + 1] = (half_t)v.y;
      Ct[r * CT_STRIDE + c4 + 2] = (half_t)v.z;
      Ct[r * CT_STRIDE + c4 + 3] = (half_t)v.w;
    }
    // csq2: k = tid>>3, 8 lanes each sum 8 d's, shuffle-reduce
    {
      int k = tid >> 3, dg = (tid & 7) * 8;
      const float* cp = ctrs + (size_t)(c * 32 + k) * DIN + dg;
      float acc = 0.0f;
#pragma unroll
      for (int j = 0; j < 8; ++j) acc = fmaf(cp[j] * cp[j], s[dg + j], acc);
      acc += __shfl_xor(acc, 1);
      acc += __shfl_xor(acc, 2);
      acc += __shfl_xor(acc, 4);
      if ((tid & 7) == 0) csq2[c * 32 + k] = acc * LOG2E;
    }
  }
  __syncthreads();

  if (w < 2) {  // 2 Vswz frags per block: sl = part*2 + w
    int sl = part * 2 + w;
    f16x8 v;
#pragma unroll
    for (int j = 0; j < 8; ++j) v[j] = Vt[(l4 * 8 + j) * 36 + w * 16 + lm];
    *(f16x8*)(Vswz + ((c * 16 + sl) * 64 + l) * 8) = v;
  }
  if (part == 0) {  // Cswz: frag f = w; ct = f>>1, kt = f&1
    int ct = w >> 1, kt = w & 1;
    f16x8 v;
#pragma unroll
    for (int j = 0; j < 8; ++j)
      v[j] = Ct[(ct * 16 + lm) * CT_STRIDE + kt * 32 + l4 * 8 + j];
    *(f16x8*)(Cswz + ((c * 4 + w) * 64 + l) * 8) = v;
  }
}

// ---------------------------------------------------------------------------
// Fused kernel, ROUND 6 = ROUND 0 (measured champion, 71us) + ONE patch:
// depth-1 prefetch of the C-frags in PASS 2 (pass 1 already had it in r0).
// Rationale (r0-r5 pipe accounting): MFMA and VALU busy-times are constant
// (~21us each) across all six schedule variants; ONLY stall time varies.
// r0's remaining naked stall was pass-2's chunk-top C-frag load, consumed
// ~10 instrs after issue (~250-300cy x 32 chunks). Everything else of r0 is
// restored byte-for-byte: two-pass softmax, per-wave P through LDS
// (8 bank conflicts/chunk = 2-way, free per m136), 4-accumulator pass-1 max,
// no barriers, no setprio, free wave drift, grid 512 x 256, bounds (256,2).
// scores = (2*cross - csq)*log2e  (x^2 term cancels in softmax).
// ---------------------------------------------------------------------------
__global__ __launch_bounds__(256, 2) void attn_kernel(
    const float* __restrict__ x, const float* __restrict__ s,
    const char* __restrict__ ws, float* __restrict__ out) {
  const half_t* Cswz = (const half_t*)(ws + CSWZ_OFF);
  const half_t* Vswz = (const half_t*)(ws + VSWZ_OFF);
  const float* csq2 = (const float*)(ws + CSQ_OFF);
  const f16x8* cbase = (const f16x8*)Cswz;
  const f16x8* vbase = (const f16x8*)Vswz;

  __shared__ half_t Plds[4 * 32 * 40];  // per-wave P (pad 40): 10240 B

  const int tid = threadIdx.x;
  const int w = tid >> 6, l = tid & 63, l4 = l >> 4, lm = l & 15;
  const int rowbase = blockIdx.x * 128 + w * 32;

  // ---- A fragments (x*s -> f16) in registers, loaded once
  f16x8 A[2][2];
#pragma unroll
  for (int rt = 0; rt < 2; ++rt) {
#pragma unroll
    for (int kt = 0; kt < 2; ++kt) {
      int din = kt * 32 + l4 * 8;
      const float* src = x + (rowbase + rt * 16 + lm) * DIN + din;
      f16x8 a;
#pragma unroll
      for (int j = 0; j < 8; ++j) a[j] = (half_t)(src[j] * s[din + j]);
      A[rt][kt] = a;
    }
  }

  // ---- all-ones B column tile (col 0), lane-constant
  f16x8 ones;
#pragma unroll
  for (int j = 0; j < 8; ++j) ones[j] = (lm == 0) ? (half_t)1.0f : (half_t)0.0f;

  // ================= PASS 1: row max =================
  float m[2][4];
#pragma unroll
  for (int rt = 0; rt < 2; ++rt)
#pragma unroll
    for (int j = 0; j < 4; ++j) m[rt][j] = -1e30f;

  {
    f16x8 nb0 = cbase[0 * 64 + l], nb1 = cbase[1 * 64 + l];
    f16x8 nb2 = cbase[2 * 64 + l], nb3 = cbase[3 * 64 + l];
    float ncs0 = csq2[lm], ncs1 = csq2[16 + lm];

    for (int c = 0; c < 32; ++c) {
      f16x8 b0 = nb0, b1 = nb1, b2 = nb2, b3 = nb3;
      float cs0 = ncs0, cs1 = ncs1;
      int cn = (c < 31) ? c + 1 : 31;  // depth-1 prefetch
      nb0 = cbase[(cn * 4 + 0) * 64 + l];
      nb1 = cbase[(cn * 4 + 1) * 64 + l];
      nb2 = cbase[(cn * 4 + 2) * 64 + l];
      nb3 = cbase[(cn * 4 + 3) * 64 + l];
      ncs0 = csq2[cn * 32 + lm];
      ncs1 = csq2[cn * 32 + 16 + lm];
#pragma unroll
      for (int rt = 0; rt < 2; ++rt) {
        f32x4 a0 = {0.f, 0.f, 0.f, 0.f}, a1 = {0.f, 0.f, 0.f, 0.f};
        a0 = __builtin_amdgcn_mfma_f32_16x16x32_f16(A[rt][0], b0, a0, 0, 0, 0);
        a0 = __builtin_amdgcn_mfma_f32_16x16x32_f16(A[rt][1], b1, a0, 0, 0, 0);
        a1 = __builtin_amdgcn_mfma_f32_16x16x32_f16(A[rt][0], b2, a1, 0, 0, 0);
        a1 = __builtin_amdgcn_mfma_f32_16x16x32_f16(A[rt][1], b3, a1, 0, 0, 0);
#pragma unroll
        for (int j = 0; j < 4; ++j) {
          float v0 = fmaf(a0[j], 2.0f * LOG2E, -cs0);
          float v1 = fmaf(a1[j], 2.0f * LOG2E, -cs1);
          m[rt][j] = fmaxf(m[rt][j], fmaxf(v0, v1));
        }
      }
    }
  }
  // reduce per-lane maxima -> exact row max (rows live in 16-lane groups)
#pragma unroll
  for (int rt = 0; rt < 2; ++rt)
#pragma unroll
    for (int j = 0; j < 4; ++j) {
      float v = m[rt][j];
      v = fmaxf(v, __shfl_xor(v, 1));
      v = fmaxf(v, __shfl_xor(v, 2));
      v = fmaxf(v, __shfl_xor(v, 4));
      v = fmaxf(v, __shfl_xor(v, 8));
      m[rt][j] = v;
    }

  // ================= PASS 2: exp + PV =================
  f32x4 O[2][16];
  f32x4 L[2];
#pragma unroll
  for (int rt = 0; rt < 2; ++rt) {
    L[rt] = (f32x4){0.f, 0.f, 0.f, 0.f};
#pragma unroll
    for (int u = 0; u < 16; ++u) O[rt][u] = (f32x4){0.f, 0.f, 0.f, 0.f};
  }

  half_t* pw = Plds + w * (32 * 40);  // wave-private P region

  {
    // ROUND-6 PATCH: depth-1 prefetch of C-frags (mirrors pass 1). csq stays
    // in-loop scalar (4KB table, L1-hot) to limit register pressure.
    f16x8 nb0 = cbase[0 * 64 + l], nb1 = cbase[1 * 64 + l];
    f16x8 nb2 = cbase[2 * 64 + l], nb3 = cbase[3 * 64 + l];

    for (int c = 0; c < 32; ++c) {
      f16x8 b0 = nb0, b1 = nb1, b2 = nb2, b3 = nb3;
      int cn = (c < 31) ? c + 1 : 31;  // depth-1 prefetch (clamped)
      nb0 = cbase[(cn * 4 + 0) * 64 + l];
      nb1 = cbase[(cn * 4 + 1) * 64 + l];
      nb2 = cbase[(cn * 4 + 2) * 64 + l];
      nb3 = cbase[(cn * 4 + 3) * 64 + l];
      float cs0 = csq2[c * 32 + lm], cs1 = csq2[c * 32 + 16 + lm];
      f16x8 pa[2];
#pragma unroll
      for (int rt = 0; rt < 2; ++rt) {
        f32x4 a0 = {0.f, 0.f, 0.f, 0.f}, a1 = {0.f, 0.f, 0.f, 0.f};
        a0 = __builtin_amdgcn_mfma_f32_16x16x32_f16(A[rt][0], b0, a0, 0, 0, 0);
        a0 = __builtin_amdgcn_mfma_f32_16x16x32_f16(A[rt][1], b1, a0, 0, 0, 0);
        a1 = __builtin_amdgcn_mfma_f32_16x16x32_f16(A[rt][0], b2, a1, 0, 0, 0);
        a1 = __builtin_amdgcn_mfma_f32_16x16x32_f16(A[rt][1], b3, a1, 0, 0, 0);
#pragma unroll
        for (int j = 0; j < 4; ++j) {
          // bitwise-identical recompute of pass-1 scores => s - m <= 0
          float v0 = fmaf(a0[j], 2.0f * LOG2E, -cs0) - m[rt][j];
          float v1 = fmaf(a1[j], 2.0f * LOG2E, -cs1) - m[rt][j];
          float p0 = __builtin_amdgcn_exp2f(v0);
          float p1 = __builtin_amdgcn_exp2f(v1);
          int pr = (rt * 16 + l4 * 4 + j) * 40 + lm;
          pw[pr] = (half_t)p0;
          pw[pr + 16] = (half_t)p1;
        }
        // P back as A-operand (same-wave LDS; DS pipe is in-order per wave)
        pa[rt] = *(const f16x8*)(pw + (rt * 16 + lm) * 40 + l4 * 8);
      }
#pragma unroll
      for (int u = 0; u < 16; ++u) {
        f16x8 vb = vbase[(c * 16 + u) * 64 + l];
        O[0][u] = __builtin_amdgcn_mfma_f32_16x16x32_f16(pa[0], vb, O[0][u], 0, 0, 0);
        O[1][u] = __builtin_amdgcn_mfma_f32_16x16x32_f16(pa[1], vb, O[1][u], 0, 0, 0);
      }
      L[0] = __builtin_amdgcn_mfma_f32_16x16x32_f16(pa[0], ones, L[0], 0, 0, 0);
      L[1] = __builtin_amdgcn_mfma_f32_16x16x32_f16(pa[1], ones, L[1], 0, 0, 0);
    }
  }

  // ---- epilogue: normalize (row sum = col 0 of L tile, lanes lm==0)
#pragma unroll
  for (int rt = 0; rt < 2; ++rt) {
#pragma unroll
    for (int j = 0; j < 4; ++j) {
      float lv = __shfl(L[rt][j], l & 48);  // broadcast from lane 16*l4
      float inv = 1.0f / fmaxf(lv, 1e-30f);
      int row = rowbase + rt * 16 + l4 * 4 + j;
      float* po = out + row * DOUT + lm;
#pragma unroll
      for (int ct = 0; ct < 16; ++ct) po[ct * 16] = O[rt][ct][j] * inv;
    }
  }
}

extern "C" void kernel_launch(void* const* d_in, const int* in_sizes, int n_in,
                              void* d_out, int out_size, void* d_ws, size_t ws_size,
                              hipStream_t stream) {
  const float* x = (const float*)d_in[0];
  const float* ctrs = (const float*)d_in[1];
  const float* values = (const float*)d_in[2];
  const float* s = (const float*)d_in[3];
  float* out = (float*)d_out;
  char* ws = (char*)d_ws;

  hipLaunchKernelGGL(precompute_kernel, dim3(256), dim3(256), 0, stream,
                     ctrs, values, s, ws);
  hipLaunchKernelGGL(attn_kernel, dim3(512), dim3(256), 0, stream,
                     x, s, ws, out);
}

// Round 8
// 137.005 us; speedup vs baseline: 1.7136x; 1.7136x over previous
//
#include <hip/hip_runtime.h>

typedef _Float16 half_t;
typedef half_t f16x8 __attribute__((ext_vector_type(8)));
typedef float f32x4 __attribute__((ext_vector_type(4)));

#define LOG2E 1.44269504088896340736f

// Problem dims (fixed)
#define NROWS 65536
#define DIN   64
#define NCTRS 1024
#define DOUT  256

// Workspace layout (bytes). ONE FRAGMENT = 64 lanes x 16 B = 1024 B.
#define CSWZ_OFF 0
#define CSWZ_BYTES (128 * 1024)
#define VSWZ_OFF (CSWZ_OFF + CSWZ_BYTES)            // 131072
#define VSWZ_BYTES (512 * 1024)
#define CSQ_OFF  (VSWZ_OFF + VSWZ_BYTES)            // 655360; end 659456

#define CT_STRIDE 68

// ---------------------------------------------------------------------------
// Precompute, 256 blocks: c = bid & 31, part = bid >> 5.
// Each block converts a 32x32 slice of V for chunk c (douts part*32..+31) into
// 2 Vswz frags. part==0 blocks additionally do Cswz + csq for chunk c.
// Fragment layout (A/B symmetric): lane holds [idx=lane&15][k=8*(lane>>4)+j].
// ---------------------------------------------------------------------------
__global__ __launch_bounds__(256) void precompute_kernel(
    const float* __restrict__ ctrs, const float* __restrict__ values,
    const float* __restrict__ s, char* __restrict__ ws) {
  half_t* Cswz = (half_t*)(ws + CSWZ_OFF);
  half_t* Vswz = (half_t*)(ws + VSWZ_OFF);
  float* csq2 = (float*)(ws + CSQ_OFF);

  __shared__ half_t Vt[32 * 36];         // 32 x 32 (+4 pad)
  __shared__ half_t Ct[32 * CT_STRIDE];  // 32 x 64 (padded)

  const int bid = blockIdx.x, tid = threadIdx.x;
  const int c = bid & 31, part = bid >> 5;
  const int w = tid >> 6, l = tid & 63, l4 = l >> 4, lm = l & 15;

  {  // V subtile: rows c*32..+31, douts part*32..+31 -> 256 float4 (1/thread)
    int r = tid >> 3, f4 = tid & 7;
    float4 v = ((const float4*)values)[(size_t)(c * 32 + r) * 64 + part * 8 + f4];
    half_t* d = Vt + r * 36 + f4 * 4;
    d[0] = (half_t)v.x; d[1] = (half_t)v.y;
    d[2] = (half_t)v.z; d[3] = (half_t)v.w;
  }
  if (part == 0) {
    // C tile: 32x64 floats = 512 float4, 2 per thread
#pragma unroll
    for (int i = 0; i < 2; ++i) {
      int idx = i * 256 + tid;
      int r = idx >> 4, c4 = (idx & 15) * 4;
      float4 v = ((const float4*)ctrs)[(size_t)(c * 32 + r) * 16 + (idx & 15)];
      Ct[r * CT_STRIDE + c4 + 0] = (half_t)v.x;
      Ct[r * CT_STRIDE + c4 + 1] = (half_t)v.y;
      Ct[r * CT_STRIDE + c4 + 2] = (half_t)v.z;
      Ct[r * CT_STRIDE + c4 + 3] = (half_t)v.w;
    }
    // csq2: k = tid>>3, 8 lanes each sum 8 d's, shuffle-reduce
    {
      int k = tid >> 3, dg = (tid & 7) * 8;
      const float* cp = ctrs + (size_t)(c * 32 + k) * DIN + dg;
      float acc = 0.0f;
#pragma unroll
      for (int j = 0; j < 8; ++j) acc = fmaf(cp[j] * cp[j], s[dg + j], acc);
      acc += __shfl_xor(acc, 1);
      acc += __shfl_xor(acc, 2);
      acc += __shfl_xor(acc, 4);
      if ((tid & 7) == 0) csq2[c * 32 + k] = acc * LOG2E;
    }
  }
  __syncthreads();

  if (w < 2) {  // 2 Vswz frags per block: sl = part*2 + w
    int sl = part * 2 + w;
    f16x8 v;
#pragma unroll
    for (int j = 0; j < 8; ++j) v[j] = Vt[(l4 * 8 + j) * 36 + w * 16 + lm];
    *(f16x8*)(Vswz + ((c * 16 + sl) * 64 + l) * 8) = v;
  }
  if (part == 0) {  // Cswz: frag f = w; ct = f>>1, kt = f&1
    int ct = w >> 1, kt = w & 1;
    f16x8 v;
#pragma unroll
    for (int j = 0; j < 8; ++j)
      v[j] = Ct[(ct * 16 + lm) * CT_STRIDE + kt * 32 + l4 * 8 + j];
    *(f16x8*)(Cswz + ((c * 4 + w) * 64 + l) * 8) = v;
  }
}

// ---------------------------------------------------------------------------
// Fused kernel, ROUND 8 = ROUND 0 CHAMPION, byte-identical (71us attn,
// 142/140.3us total, passed). Restored after r6 falsified the prefetch
// theory: r0 sits exactly at the 256-reg cliff (128 VGPR + ~128 AGPR for O);
// ANY extra live state (r6: +16 regs) makes the allocator de-pipeline the
// in-loop V-frag hoisting (VGPR 128->112, MfmaUtil 30->13, dur 71->170us).
// Evidence r0-r7: MFMA busy ~21us and VALU busy ~21us are invariant across
// all structural variants; only stall time differs; occupancy is grid-bound
// (2048 waves = 2/SIMD). This schedule minimizes stalls by giving the
// compiler maximal register freedom: no barriers, free wave drift, two-pass
// softmax (no serial online-softmax machinery), P via same-wave LDS
// round-trip (2-way bank aliasing = free per m136).
// scores = (2*cross - csq)*log2e  (x^2 term cancels in softmax).
// ---------------------------------------------------------------------------
__global__ __launch_bounds__(256, 2) void attn_kernel(
    const float* __restrict__ x, const float* __restrict__ s,
    const char* __restrict__ ws, float* __restrict__ out) {
  const half_t* Cswz = (const half_t*)(ws + CSWZ_OFF);
  const half_t* Vswz = (const half_t*)(ws + VSWZ_OFF);
  const float* csq2 = (const float*)(ws + CSQ_OFF);
  const f16x8* cbase = (const f16x8*)Cswz;
  const f16x8* vbase = (const f16x8*)Vswz;

  __shared__ half_t Plds[4 * 32 * 40];  // per-wave P (pad 40): 10240 B

  const int tid = threadIdx.x;
  const int w = tid >> 6, l = tid & 63, l4 = l >> 4, lm = l & 15;
  const int rowbase = blockIdx.x * 128 + w * 32;

  // ---- A fragments (x*s -> f16) in registers, loaded once
  f16x8 A[2][2];
#pragma unroll
  for (int rt = 0; rt < 2; ++rt) {
#pragma unroll
    for (int kt = 0; kt < 2; ++kt) {
      int din = kt * 32 + l4 * 8;
      const float* src = x + (rowbase + rt * 16 + lm) * DIN + din;
      f16x8 a;
#pragma unroll
      for (int j = 0; j < 8; ++j) a[j] = (half_t)(src[j] * s[din + j]);
      A[rt][kt] = a;
    }
  }

  // ---- all-ones B column tile (col 0), lane-constant
  f16x8 ones;
#pragma unroll
  for (int j = 0; j < 8; ++j) ones[j] = (lm == 0) ? (half_t)1.0f : (half_t)0.0f;

  // ================= PASS 1: row max =================
  float m[2][4];
#pragma unroll
  for (int rt = 0; rt < 2; ++rt)
#pragma unroll
    for (int j = 0; j < 4; ++j) m[rt][j] = -1e30f;

  f16x8 nb0 = cbase[0 * 64 + l], nb1 = cbase[1 * 64 + l];
  f16x8 nb2 = cbase[2 * 64 + l], nb3 = cbase[3 * 64 + l];
  float ncs0 = csq2[lm], ncs1 = csq2[16 + lm];

  for (int c = 0; c < 32; ++c) {
    f16x8 b0 = nb0, b1 = nb1, b2 = nb2, b3 = nb3;
    float cs0 = ncs0, cs1 = ncs1;
    int cn = (c < 31) ? c + 1 : 31;  // depth-1 prefetch
    nb0 = cbase[(cn * 4 + 0) * 64 + l];
    nb1 = cbase[(cn * 4 + 1) * 64 + l];
    nb2 = cbase[(cn * 4 + 2) * 64 + l];
    nb3 = cbase[(cn * 4 + 3) * 64 + l];
    ncs0 = csq2[cn * 32 + lm];
    ncs1 = csq2[cn * 32 + 16 + lm];
#pragma unroll
    for (int rt = 0; rt < 2; ++rt) {
      f32x4 a0 = {0.f, 0.f, 0.f, 0.f}, a1 = {0.f, 0.f, 0.f, 0.f};
      a0 = __builtin_amdgcn_mfma_f32_16x16x32_f16(A[rt][0], b0, a0, 0, 0, 0);
      a0 = __builtin_amdgcn_mfma_f32_16x16x32_f16(A[rt][1], b1, a0, 0, 0, 0);
      a1 = __builtin_amdgcn_mfma_f32_16x16x32_f16(A[rt][0], b2, a1, 0, 0, 0);
      a1 = __builtin_amdgcn_mfma_f32_16x16x32_f16(A[rt][1], b3, a1, 0, 0, 0);
#pragma unroll
      for (int j = 0; j < 4; ++j) {
        float v0 = fmaf(a0[j], 2.0f * LOG2E, -cs0);
        float v1 = fmaf(a1[j], 2.0f * LOG2E, -cs1);
        m[rt][j] = fmaxf(m[rt][j], fmaxf(v0, v1));
      }
    }
  }
  // reduce per-lane maxima -> exact row max (rows live in 16-lane groups)
#pragma unroll
  for (int rt = 0; rt < 2; ++rt)
#pragma unroll
    for (int j = 0; j < 4; ++j) {
      float v = m[rt][j];
      v = fmaxf(v, __shfl_xor(v, 1));
      v = fmaxf(v, __shfl_xor(v, 2));
      v = fmaxf(v, __shfl_xor(v, 4));
      v = fmaxf(v, __shfl_xor(v, 8));
      m[rt][j] = v;
    }

  // ================= PASS 2: exp + PV =================
  f32x4 O[2][16];
  f32x4 L[2];
#pragma unroll
  for (int rt = 0; rt < 2; ++rt) {
    L[rt] = (f32x4){0.f, 0.f, 0.f, 0.f};
#pragma unroll
    for (int u = 0; u < 16; ++u) O[rt][u] = (f32x4){0.f, 0.f, 0.f, 0.f};
  }

  half_t* pw = Plds + w * (32 * 40);  // wave-private P region

  for (int c = 0; c < 32; ++c) {
    f16x8 b0 = cbase[(c * 4 + 0) * 64 + l];
    f16x8 b1 = cbase[(c * 4 + 1) * 64 + l];
    f16x8 b2 = cbase[(c * 4 + 2) * 64 + l];
    f16x8 b3 = cbase[(c * 4 + 3) * 64 + l];
    float cs0 = csq2[c * 32 + lm], cs1 = csq2[c * 32 + 16 + lm];
    f16x8 pa[2];
#pragma unroll
    for (int rt = 0; rt < 2; ++rt) {
      f32x4 a0 = {0.f, 0.f, 0.f, 0.f}, a1 = {0.f, 0.f, 0.f, 0.f};
      a0 = __builtin_amdgcn_mfma_f32_16x16x32_f16(A[rt][0], b0, a0, 0, 0, 0);
      a0 = __builtin_amdgcn_mfma_f32_16x16x32_f16(A[rt][1], b1, a0, 0, 0, 0);
      a1 = __builtin_amdgcn_mfma_f32_16x16x32_f16(A[rt][0], b2, a1, 0, 0, 0);
      a1 = __builtin_amdgcn_mfma_f32_16x16x32_f16(A[rt][1], b3, a1, 0, 0, 0);
#pragma unroll
      for (int j = 0; j < 4; ++j) {
        // bitwise-identical recompute of pass-1 scores => s - m <= 0
        float v0 = fmaf(a0[j], 2.0f * LOG2E, -cs0) - m[rt][j];
        float v1 = fmaf(a1[j], 2.0f * LOG2E, -cs1) - m[rt][j];
        float p0 = __builtin_amdgcn_exp2f(v0);
        float p1 = __builtin_amdgcn_exp2f(v1);
        int pr = (rt * 16 + l4 * 4 + j) * 40 + lm;
        pw[pr] = (half_t)p0;
        pw[pr + 16] = (half_t)p1;
      }
      // P back as A-operand (same-wave LDS; DS pipe is in-order per wave)
      pa[rt] = *(const f16x8*)(pw + (rt * 16 + lm) * 40 + l4 * 8);
    }
#pragma unroll
    for (int u = 0; u < 16; ++u) {
      f16x8 vb = vbase[(c * 16 + u) * 64 + l];
      O[0][u] = __builtin_amdgcn_mfma_f32_16x16x32_f16(pa[0], vb, O[0][u], 0, 0, 0);
      O[1][u] = __builtin_amdgcn_mfma_f32_16x16x32_f16(pa[1], vb, O[1][u], 0, 0, 0);
    }
    L[0] = __builtin_amdgcn_mfma_f32_16x16x32_f16(pa[0], ones, L[0], 0, 0, 0);
    L[1] = __builtin_amdgcn_mfma_f32_16x16x32_f16(pa[1], ones, L[1], 0, 0, 0);
  }

  // ---- epilogue: normalize (row sum = col 0 of L tile, lanes lm==0)
#pragma unroll
  for (int rt = 0; rt < 2; ++rt) {
#pragma unroll
    for (int j = 0; j < 4; ++j) {
      float lv = __shfl(L[rt][j], l & 48);  // broadcast from lane 16*l4
      float inv = 1.0f / fmaxf(lv, 1e-30f);
      int row = rowbase + rt * 16 + l4 * 4 + j;
      float* po = out + row * DOUT + lm;
#pragma unroll
      for (int ct = 0; ct < 16; ++ct) po[ct * 16] = O[rt][ct][j] * inv;
    }
  }
}

extern "C" void kernel_launch(void* const* d_in, const int* in_sizes, int n_in,
                              void* d_out, int out_size, void* d_ws, size_t ws_size,
                              hipStream_t stream) {
  const float* x = (const float*)d_in[0];
  const float* ctrs = (const float*)d_in[1];
  const float* values = (const float*)d_in[2];
  const float* s = (const float*)d_in[3];
  float* out = (float*)d_out;
  char* ws = (char*)d_ws;

  hipLaunchKernelGGL(precompute_kernel, dim3(256), dim3(256), 0, stream,
                     ctrs, values, s, ws);
  hipLaunchKernelGGL(attn_kernel, dim3(512), dim3(256), 0, stream,
                     x, s, ws, out);
}